// Round 1
// baseline (71.051 us; speedup 1.0000x reference)
//
#include <hip/hip_runtime.h>
#include <math.h>

#define N_CAM 6
#define C_IN 256
#define C_OUT 80
#define FH 32
#define FW 88
#define NXG 200
#define NYG 200
#define S_SPATIAL (NXG*NYG)        // 40000
#define POS_PER_CAM (FH*FW)        // 2816
#define NPOS (N_CAM*POS_PER_CAM)   // 16896

// ws layout (in floats)
#define WS_PA    0      // 84 floats: proj[6][12] + aug[6][2]
#define WS_BIAS  128    // 80 floats
#define WS_W2    256    // 80*256 = 20480 floats
#define WS_FEAT2 20992  // NPOS*80 = 1,351,680 floats (~5.4 MB)

// ---------------- kernel 1: per-camera projection matrices ----------------
__global__ void k_setup(const float* __restrict__ iam,
                        const float* __restrict__ lam,
                        const float* __restrict__ l2i,
                        float* __restrict__ pa) {
    int n = threadIdx.x;
    if (n >= N_CAM) return;
    const float* A = iam + n * 16;   // img_aug_matrix (last col zeroed for proj)
    const float* L = l2i + n * 16;   // lidar2image
    // M1 = iam_r @ l2i  (iam_r[i][3] = 0, so k=3 term drops). FMA chain ~= BLAS sgemm.
    float M1[12];
    #pragma unroll
    for (int i = 0; i < 3; ++i) {
        #pragma unroll
        for (int j = 0; j < 4; ++j) {
            float acc = __fmul_rn(A[i*4+0], L[0*4+j]);
            acc = __fmaf_rn(A[i*4+1], L[1*4+j], acc);
            acc = __fmaf_rn(A[i*4+2], L[2*4+j], acc);
            M1[i*4+j] = acc;
        }
    }
    // proj = M1 @ lam, rows 0..2
    #pragma unroll
    for (int i = 0; i < 3; ++i) {
        #pragma unroll
        for (int j = 0; j < 4; ++j) {
            float acc = __fmul_rn(M1[i*4+0], lam[0*4+j]);
            acc = __fmaf_rn(M1[i*4+1], lam[1*4+j], acc);
            acc = __fmaf_rn(M1[i*4+2], lam[2*4+j], acc);
            acc = __fmaf_rn(M1[i*4+3], lam[3*4+j], acc);
            pa[n*12 + i*4 + j] = acc;
        }
    }
    pa[72 + n*2 + 0] = A[0*4 + 3];   // aug_t x (from unmodified iam)
    pa[72 + n*2 + 1] = A[1*4 + 3];   // aug_t y
}

// ---------------- kernel 2: fold BN into conv weights ----------------
__global__ void k_w2(const float* __restrict__ conv_w, const float* __restrict__ conv_b,
                     const float* __restrict__ gamma, const float* __restrict__ beta,
                     const float* __restrict__ mean, const float* __restrict__ var,
                     float* __restrict__ w2, float* __restrict__ bias2) {
    int o = blockIdx.x;
    int t = threadIdx.x;
    float inv = 1.0f / sqrtf(var[o] + 1e-5f);
    float sc = __fmul_rn(inv, gamma[o]);
    w2[o * C_IN + t] = __fmul_rn(conv_w[o * C_IN + t], sc);
    if (t == 0) {
        bias2[o] = __fadd_rn(__fmul_rn(__fsub_rn(conv_b[o], mean[o]), sc), beta[o]);
    }
}

// ---------------- kernel 3: feat2[n,v,u,o] = sum_c w2[o,c]*feat[n,c,v,u] ----------------
#define CK 32
__global__ __launch_bounds__(256) void k_conv(const float* __restrict__ feat,
                                              const float* __restrict__ w2,
                                              float* __restrict__ feat2) {
    __shared__ float ftile[CK][64];
    __shared__ float w2t[C_OUT][CK];
    int b = blockIdx.x;          // 264 blocks; 44 tiles of 64 positions per camera
    int n = b / 44;
    int vu0 = (b % 44) * 64;
    int t = threadIdx.x;
    int pl = t & 63;             // position within tile
    int og = t >> 6;             // 0..3, 20 outputs each
    float acc[20];
    #pragma unroll
    for (int k = 0; k < 20; ++k) acc[k] = 0.0f;

    for (int c0 = 0; c0 < C_IN; c0 += CK) {
        __syncthreads();
        #pragma unroll
        for (int j = 0; j < 8; ++j) {          // 32x64 feat tile, coalesced
            int e = j * 256 + t;
            int cc = e >> 6, p = e & 63;
            ftile[cc][p] = feat[(n * C_IN + c0 + cc) * POS_PER_CAM + vu0 + p];
        }
        #pragma unroll
        for (int j = 0; j < 10; ++j) {         // 80x32 w2 tile, coalesced
            int e = j * 256 + t;
            int o = e >> 5, cc = e & 31;
            w2t[o][cc] = w2[o * C_IN + c0 + cc];
        }
        __syncthreads();
        #pragma unroll
        for (int cc = 0; cc < CK; ++cc) {
            float f = ftile[cc][pl];
            #pragma unroll
            for (int k = 0; k < 20; ++k)
                acc[k] = __fmaf_rn(w2t[og * 20 + k][cc], f, acc[k]);
        }
    }
    float* dst = feat2 + (n * POS_PER_CAM + vu0 + pl) * C_OUT + og * 20;
    #pragma unroll
    for (int q = 0; q < 5; ++q) {
        *reinterpret_cast<float4*>(dst + 4 * q) =
            make_float4(acc[4*q], acc[4*q+1], acc[4*q+2], acc[4*q+3]);
    }
}

// ---------------- kernel 4: backproject + weighted z-sum + bias + relu ----------------
__global__ __launch_bounds__(256) void k_main(const float* __restrict__ feat2,
                                              const float* __restrict__ pa_g,
                                              const float* __restrict__ bias_g,
                                              const float* __restrict__ points,
                                              float* __restrict__ out) {
    __shared__ float s_pa[84];
    __shared__ float s_bias[C_OUT];
    __shared__ int   s_base[64];
    __shared__ float s_w[64];
    __shared__ float s_y[16 * 81];   // stride 81: conflict-free transpose
    int t = threadIdx.x;
    int col0 = blockIdx.x * 16;

    if (t < 84) s_pa[t] = pa_g[t];
    else if (t >= 128 && t < 128 + C_OUT) s_bias[t - 128] = bias_g[t - 128];
    __syncthreads();

    // phase 1: per (column, z) camera selection — fp32 mimicking numpy op order
    if (t < 64) {
        int cl = t >> 2, z = t & 3;
        int col = col0 + cl;
        int ix = col / NYG, iy = col % NYG;
        float x  = (float)ix * 0.5f - 50.0f;   // exact dyadic
        float y  = (float)iy * 0.5f - 50.0f;
        float zc = (float)z  * 1.5f - 4.0f;
        int sel_base = 0;
        bool any = false;
        #pragma unroll
        for (int n = 0; n < N_CAM; ++n) {
            const float* P = s_pa + n * 12;
            // sequential non-fused mul/add: matches np.einsum (no FMA, j ascending)
            float px = __fadd_rn(__fadd_rn(__fadd_rn(__fmul_rn(P[0], x), __fmul_rn(P[1], y)), __fmul_rn(P[2], zc)), P[3]);
            float py = __fadd_rn(__fadd_rn(__fadd_rn(__fmul_rn(P[4], x), __fmul_rn(P[5], y)), __fmul_rn(P[6], zc)), P[7]);
            float pz = __fadd_rn(__fadd_rn(__fadd_rn(__fmul_rn(P[8], x), __fmul_rn(P[9], y)), __fmul_rn(P[10], zc)), P[11]);
            float Z = pz;
            float Zs = (fabsf(Z) > 1e-6f) ? Z : 1e-6f;
            float u = __fadd_rn(px / Zs, s_pa[72 + n*2 + 0]);
            float v = __fadd_rn(py / Zs, s_pa[72 + n*2 + 1]);
            float uf = rintf(__fmul_rn(u, 0.125f));   // u/8 exact; rintf = half-even = np.round
            float vf = rintf(__fmul_rn(v, 0.125f));
            int ui = (int)uf, vi = (int)vf;           // saturating cvt; out-of-range stays invalid
            bool val = (ui >= 0) & (vi >= 0) & (ui < FW) & (vi < FH) & (Z > 0.0f);
            if (val) { sel_base = ((n * FH + vi) * FW + ui) * C_OUT; any = true; }  // last valid wins
        }
        float w = 0.0f;
        if (any) w = points[z * S_SPATIAL + col];
        else sel_base = 0;
        s_base[t] = sel_base;
        s_w[t] = w;
    }
    __syncthreads();

    // phase 2: gather 80 contiguous floats per (col,z), weighted z-sum, bias, relu
    #pragma unroll
    for (int it = 0; it < 5; ++it) {
        int idx = it * 256 + t;            // 16 cols * 80 outs = 1280
        int cl = idx / 80, o = idx - cl * 80;
        float acc =            __fmul_rn(s_w[cl*4+0], feat2[s_base[cl*4+0] + o]);
        acc = __fadd_rn(acc, __fmul_rn(s_w[cl*4+1], feat2[s_base[cl*4+1] + o]));
        acc = __fadd_rn(acc, __fmul_rn(s_w[cl*4+2], feat2[s_base[cl*4+2] + o]));
        acc = __fadd_rn(acc, __fmul_rn(s_w[cl*4+3], feat2[s_base[cl*4+3] + o]));
        float yv = fmaxf(__fadd_rn(acc, s_bias[o]), 0.0f);
        s_y[cl * 81 + o] = yv;
    }
    __syncthreads();

    // phase 3: transposed write — coalesced 16-float segments per o
    #pragma unroll
    for (int it = 0; it < 5; ++it) {
        int idx = it * 256 + t;
        int o = idx >> 4, cl = idx & 15;
        out[o * S_SPATIAL + col0 + cl] = s_y[cl * 81 + o];
    }
}

extern "C" void kernel_launch(void* const* d_in, const int* in_sizes, int n_in,
                              void* d_out, int out_size, void* d_ws, size_t ws_size,
                              hipStream_t stream) {
    const float* feat   = (const float*)d_in[0];   // (1,6,256,32,88)
    const float* points = (const float*)d_in[1];   // (1,4,200,200)
    const float* l2i    = (const float*)d_in[5];   // lidar2image (1,6,4,4)
    const float* iam    = (const float*)d_in[8];   // img_aug_matrix (1,6,4,4)
    const float* lam    = (const float*)d_in[9];   // lidar_aug_matrix (1,4,4)
    const float* conv_w = (const float*)d_in[11];  // (80,256)
    const float* conv_b = (const float*)d_in[12];
    const float* gamma  = (const float*)d_in[13];
    const float* beta   = (const float*)d_in[14];
    const float* mean   = (const float*)d_in[15];
    const float* var    = (const float*)d_in[16];

    float* ws    = (float*)d_ws;
    float* pa    = ws + WS_PA;
    float* bias2 = ws + WS_BIAS;
    float* w2    = ws + WS_W2;
    float* feat2 = ws + WS_FEAT2;
    float* out   = (float*)d_out;

    hipLaunchKernelGGL(k_setup, dim3(1), dim3(64), 0, stream, iam, lam, l2i, pa);
    hipLaunchKernelGGL(k_w2, dim3(C_OUT), dim3(C_IN), 0, stream,
                       conv_w, conv_b, gamma, beta, mean, var, w2, bias2);
    hipLaunchKernelGGL(k_conv, dim3(NPOS / 64), dim3(256), 0, stream, feat, w2, feat2);
    hipLaunchKernelGGL(k_main, dim3(S_SPATIAL / 16), dim3(256), 0, stream,
                       feat2, pa, bias2, points, out);
}

// Round 2
// 52.217 us; speedup vs baseline: 1.3607x; 1.3607x over previous
//
#include <hip/hip_runtime.h>
#include <math.h>

#define N_CAM 6
#define C_IN 256
#define C_OUT 80
#define FH 32
#define FW 88
#define NXG 200
#define NYG 200
#define S_SPATIAL (NXG*NYG)        // 40000
#define POS_PER_CAM (FH*FW)        // 2816
#define NPOS (N_CAM*POS_PER_CAM)   // 16896

// ws layout (in floats)
#define WS_PA    0      // 84 floats: proj[6][12] + aug[6][2]
#define WS_BIAS  128    // 80 floats
#define WS_W2T   256    // transposed w2t[c][o]: 256*80 = 20480 floats
#define WS_FEAT2 20736  // NPOS*80 = 1,351,680 floats (~5.4 MB)

// ---------------- kernel 1: projection matrices + BN-folded transposed weights ----------------
__global__ void k_prep(const float* __restrict__ iam,
                       const float* __restrict__ lam,
                       const float* __restrict__ l2i,
                       const float* __restrict__ conv_w, const float* __restrict__ conv_b,
                       const float* __restrict__ gamma, const float* __restrict__ beta,
                       const float* __restrict__ mean, const float* __restrict__ var,
                       float* __restrict__ pa, float* __restrict__ w2t,
                       float* __restrict__ bias2) {
    int bid = blockIdx.x;
    int t = threadIdx.x;
    if (bid == 0) {
        // per-camera projection matrices (6 threads)
        if (t >= N_CAM) return;
        int n = t;
        const float* A = iam + n * 16;   // img_aug_matrix (last col zeroed for proj)
        const float* L = l2i + n * 16;   // lidar2image
        float M1[12];
        #pragma unroll
        for (int i = 0; i < 3; ++i) {
            #pragma unroll
            for (int j = 0; j < 4; ++j) {
                float acc = __fmul_rn(A[i*4+0], L[0*4+j]);
                acc = __fmaf_rn(A[i*4+1], L[1*4+j], acc);
                acc = __fmaf_rn(A[i*4+2], L[2*4+j], acc);
                M1[i*4+j] = acc;
            }
        }
        #pragma unroll
        for (int i = 0; i < 3; ++i) {
            #pragma unroll
            for (int j = 0; j < 4; ++j) {
                float acc = __fmul_rn(M1[i*4+0], lam[0*4+j]);
                acc = __fmaf_rn(M1[i*4+1], lam[1*4+j], acc);
                acc = __fmaf_rn(M1[i*4+2], lam[2*4+j], acc);
                acc = __fmaf_rn(M1[i*4+3], lam[3*4+j], acc);
                pa[n*12 + i*4 + j] = acc;
            }
        }
        pa[72 + n*2 + 0] = A[0*4 + 3];
        pa[72 + n*2 + 1] = A[1*4 + 3];
    } else {
        // fold BN into conv weights, store TRANSPOSED: w2t[c*80 + o]
        int o = bid - 1;                 // 0..79
        float inv = 1.0f / sqrtf(var[o] + 1e-5f);
        float sc = __fmul_rn(inv, gamma[o]);
        w2t[t * C_OUT + o] = __fmul_rn(conv_w[o * C_IN + t], sc);
        if (t == 0) {
            bias2[o] = __fadd_rn(__fmul_rn(__fsub_rn(conv_b[o], mean[o]), sc), beta[o]);
        }
    }
}

// ---------------- kernel 2: feat2[n,v,u,o] = sum_c w2[o,c]*feat[n,c,v,u] ----------------
// 264 blocks x 256 threads. Per thread: 1 position x 20 outputs.
// w2 comes from SGPRs (uniform index via readfirstlane -> s_load), feat from LDS (1 b32/cc).
#define CK 64
__global__ __launch_bounds__(256) void k_conv(const float* __restrict__ feat,
                                              const float* __restrict__ w2t,
                                              float* __restrict__ feat2) {
    __shared__ float ftile[2][CK][64];     // 32 KiB double buffer
    int b = blockIdx.x;                    // 264 = 6 cams * 44 tiles
    int n = b / 44;
    int vu0 = (b % 44) * 64;
    int t = threadIdx.x;
    int pl = t & 63;                       // position within tile
    int sg = t >> 6;                       // wave id 0..3 -> 20 outputs each
    int wbase = __builtin_amdgcn_readfirstlane(sg * 20);  // wave-uniform -> SGPR
    const float* feat_n = feat + (size_t)n * C_IN * POS_PER_CAM + vu0;

    float acc[20];
    #pragma unroll
    for (int k = 0; k < 20; ++k) acc[k] = 0.0f;

    // prologue: stage chunk 0
    #pragma unroll
    for (int j = 0; j < 4; ++j) {
        int f = j * 256 + t;
        int cc = f >> 4, p4 = (f & 15) << 2;
        *reinterpret_cast<float4*>(&ftile[0][cc][p4]) =
            *reinterpret_cast<const float4*>(feat_n + (size_t)cc * POS_PER_CAM + p4);
    }
    __syncthreads();

    int cur = 0;
    #pragma unroll 1
    for (int chunk = 0; chunk < 4; ++chunk) {
        // T14 async-stage: issue next chunk's global loads now (complete under compute)
        float4 pf0, pf1, pf2, pf3;
        if (chunk < 3) {
            int c1 = (chunk + 1) * CK;
            {int f = 0*256+t; int cc=f>>4, p4=(f&15)<<2; pf0 = *reinterpret_cast<const float4*>(feat_n + (size_t)(c1+cc)*POS_PER_CAM + p4);}
            {int f = 1*256+t; int cc=f>>4, p4=(f&15)<<2; pf1 = *reinterpret_cast<const float4*>(feat_n + (size_t)(c1+cc)*POS_PER_CAM + p4);}
            {int f = 2*256+t; int cc=f>>4, p4=(f&15)<<2; pf2 = *reinterpret_cast<const float4*>(feat_n + (size_t)(c1+cc)*POS_PER_CAM + p4);}
            {int f = 3*256+t; int cc=f>>4, p4=(f&15)<<2; pf3 = *reinterpret_cast<const float4*>(feat_n + (size_t)(c1+cc)*POS_PER_CAM + p4);}
        }
        // compute: per cc, 1 ds_read_b32 + 20 FMA with s_loaded weights
        const float* wrow = w2t + (size_t)chunk * CK * C_OUT + wbase;   // uniform
        #pragma unroll 1
        for (int cc8 = 0; cc8 < CK; cc8 += 8) {
            #pragma unroll
            for (int u = 0; u < 8; ++u) {
                float f = ftile[cur][cc8 + u][pl];
                #pragma unroll
                for (int k = 0; k < 20; ++k)
                    acc[k] = __fmaf_rn(wrow[(cc8 + u) * C_OUT + k], f, acc[k]);
            }
        }
        // write the prefetched chunk into the other buffer
        if (chunk < 3) {
            {int f = 0*256+t; int cc=f>>4, p4=(f&15)<<2; *reinterpret_cast<float4*>(&ftile[cur^1][cc][p4]) = pf0;}
            {int f = 1*256+t; int cc=f>>4, p4=(f&15)<<2; *reinterpret_cast<float4*>(&ftile[cur^1][cc][p4]) = pf1;}
            {int f = 2*256+t; int cc=f>>4, p4=(f&15)<<2; *reinterpret_cast<float4*>(&ftile[cur^1][cc][p4]) = pf2;}
            {int f = 3*256+t; int cc=f>>4, p4=(f&15)<<2; *reinterpret_cast<float4*>(&ftile[cur^1][cc][p4]) = pf3;}
        }
        __syncthreads();
        cur ^= 1;
    }

    float* dst = feat2 + ((size_t)n * POS_PER_CAM + vu0 + pl) * C_OUT + wbase;
    #pragma unroll
    for (int q = 0; q < 5; ++q) {
        *reinterpret_cast<float4*>(dst + 4 * q) =
            make_float4(acc[4*q], acc[4*q+1], acc[4*q+2], acc[4*q+3]);
    }
}

// ---------------- kernel 3: backproject + weighted z-sum + bias + relu ----------------
__global__ __launch_bounds__(256) void k_main(const float* __restrict__ feat2,
                                              const float* __restrict__ pa_g,
                                              const float* __restrict__ bias_g,
                                              const float* __restrict__ points,
                                              float* __restrict__ out) {
    __shared__ float s_pa[84];
    __shared__ float s_bias[C_OUT];
    __shared__ int   s_base[64];
    __shared__ float s_w[64];
    __shared__ float s_y[16 * 81];   // stride 81: conflict-free transpose
    int t = threadIdx.x;
    int col0 = blockIdx.x * 16;

    if (t < 84) s_pa[t] = pa_g[t];
    else if (t >= 128 && t < 128 + C_OUT) s_bias[t - 128] = bias_g[t - 128];
    __syncthreads();

    // phase 1: per (column, z) camera selection — fp32 mimicking numpy op order
    if (t < 64) {
        int cl = t >> 2, z = t & 3;
        int col = col0 + cl;
        int ix = col / NYG, iy = col % NYG;
        float x  = (float)ix * 0.5f - 50.0f;   // exact dyadic
        float y  = (float)iy * 0.5f - 50.0f;
        float zc = (float)z  * 1.5f - 4.0f;
        int sel_base = 0;
        bool any = false;
        #pragma unroll
        for (int n = 0; n < N_CAM; ++n) {
            const float* P = s_pa + n * 12;
            // sequential non-fused mul/add: matches np.einsum (no FMA, j ascending)
            float px = __fadd_rn(__fadd_rn(__fadd_rn(__fmul_rn(P[0], x), __fmul_rn(P[1], y)), __fmul_rn(P[2], zc)), P[3]);
            float py = __fadd_rn(__fadd_rn(__fadd_rn(__fmul_rn(P[4], x), __fmul_rn(P[5], y)), __fmul_rn(P[6], zc)), P[7]);
            float pz = __fadd_rn(__fadd_rn(__fadd_rn(__fmul_rn(P[8], x), __fmul_rn(P[9], y)), __fmul_rn(P[10], zc)), P[11]);
            float Z = pz;
            float Zs = (fabsf(Z) > 1e-6f) ? Z : 1e-6f;
            float u = __fadd_rn(px / Zs, s_pa[72 + n*2 + 0]);
            float v = __fadd_rn(py / Zs, s_pa[72 + n*2 + 1]);
            float uf = rintf(__fmul_rn(u, 0.125f));   // u/8 exact; rintf = half-even = np.round
            float vf = rintf(__fmul_rn(v, 0.125f));
            int ui = (int)uf, vi = (int)vf;           // saturating cvt; out-of-range stays invalid
            bool val = (ui >= 0) & (vi >= 0) & (ui < FW) & (vi < FH) & (Z > 0.0f);
            if (val) { sel_base = ((n * FH + vi) * FW + ui) * C_OUT; any = true; }  // last valid wins
        }
        float w = 0.0f;
        if (any) w = points[z * S_SPATIAL + col];
        else sel_base = 0;
        s_base[t] = sel_base;
        s_w[t] = w;
    }
    __syncthreads();

    // phase 2: gather 80 contiguous floats per (col,z), weighted z-sum, bias, relu
    #pragma unroll
    for (int it = 0; it < 5; ++it) {
        int idx = it * 256 + t;            // 16 cols * 80 outs = 1280
        int cl = idx / 80, o = idx - cl * 80;
        float acc =            __fmul_rn(s_w[cl*4+0], feat2[s_base[cl*4+0] + o]);
        acc = __fadd_rn(acc, __fmul_rn(s_w[cl*4+1], feat2[s_base[cl*4+1] + o]));
        acc = __fadd_rn(acc, __fmul_rn(s_w[cl*4+2], feat2[s_base[cl*4+2] + o]));
        acc = __fadd_rn(acc, __fmul_rn(s_w[cl*4+3], feat2[s_base[cl*4+3] + o]));
        float yv = fmaxf(__fadd_rn(acc, s_bias[o]), 0.0f);
        s_y[cl * 81 + o] = yv;
    }
    __syncthreads();

    // phase 3: transposed write — coalesced 16-float segments per o
    #pragma unroll
    for (int it = 0; it < 5; ++it) {
        int idx = it * 256 + t;
        int o = idx >> 4, cl = idx & 15;
        out[o * S_SPATIAL + col0 + cl] = s_y[cl * 81 + o];
    }
}

extern "C" void kernel_launch(void* const* d_in, const int* in_sizes, int n_in,
                              void* d_out, int out_size, void* d_ws, size_t ws_size,
                              hipStream_t stream) {
    const float* feat   = (const float*)d_in[0];   // (1,6,256,32,88)
    const float* points = (const float*)d_in[1];   // (1,4,200,200)
    const float* l2i    = (const float*)d_in[5];   // lidar2image (1,6,4,4)
    const float* iam    = (const float*)d_in[8];   // img_aug_matrix (1,6,4,4)
    const float* lam    = (const float*)d_in[9];   // lidar_aug_matrix (1,4,4)
    const float* conv_w = (const float*)d_in[11];  // (80,256)
    const float* conv_b = (const float*)d_in[12];
    const float* gamma  = (const float*)d_in[13];
    const float* beta   = (const float*)d_in[14];
    const float* mean   = (const float*)d_in[15];
    const float* var    = (const float*)d_in[16];

    float* ws    = (float*)d_ws;
    float* pa    = ws + WS_PA;
    float* bias2 = ws + WS_BIAS;
    float* w2t   = ws + WS_W2T;
    float* feat2 = ws + WS_FEAT2;
    float* out   = (float*)d_out;

    hipLaunchKernelGGL(k_prep, dim3(1 + C_OUT), dim3(256), 0, stream,
                       iam, lam, l2i, conv_w, conv_b, gamma, beta, mean, var,
                       pa, w2t, bias2);
    hipLaunchKernelGGL(k_conv, dim3(NPOS / 64), dim3(256), 0, stream, feat, w2t, feat2);
    hipLaunchKernelGGL(k_main, dim3(S_SPATIAL / 16), dim3(256), 0, stream,
                       feat2, pa, bias2, points, out);
}